// Round 4
// baseline (794.949 us; speedup 1.0000x reference)
//
#include <hip/hip_runtime.h>
#include <hip/hip_bf16.h>
#include <hip/hip_cooperative_groups.h>

namespace cg = cooperative_groups;

// DigitCaps dynamic routing. Output fp32.
// R17: single cooperative mega-kernel. R16 post-mortem: halving traffic was
// neutral -> ~108us of the 178 is dispatch-boundary overhead (11 dispatches,
// ~10us each). Fuse all phases into one kernel with grid.sync() (10 syncs).
// Phase bodies identical to verified R16 kernels, wrapped in grid-stride
// loops. Fallback to the 11-dispatch chain if cooperative launch fails.
#define B 512
#define IC 1152
#define QD 8
#define OD 10
#define PD 16
#define KD (IC * QD)       // 9216
#define NKB (KD / 32)      // 288 K32 blocks
#define NCS 72             // K-chunks for s GEMM; 288/72 = 4 K-steps
#define KSTEPS (NKB / NCS)
#define NCB 4              // b-chunks for agreement GEMM (128 each)
#define SOP (B * OD * PD)  // 81920
#define IO (IC * OD)       // 11520
#define TPX ((B / 64) * (KD / 64))  // 8*144 = 1152 transpose tiles
#define NBTARGET 576

typedef short bf16x8 __attribute__((ext_vector_type(8)));
typedef short bf16x4 __attribute__((ext_vector_type(4)));
typedef float f32x4 __attribute__((ext_vector_type(4)));

__device__ __forceinline__ short f2bf(float f) {
  union { float f; unsigned u; } x;
  x.f = f;
  unsigned r = x.u + 0x7FFFu + ((x.u >> 16) & 1u);  // RNE to bf16
  return (short)(r >> 16);
}

__device__ __forceinline__ void bs_elem(const float* __restrict__ W, short* __restrict__ Bs,
                                        int t, const float cw[4]) {
  const int kb = t / 160, n = t % 160;
  const int o = n >> 4, p = n & 15;
  short ov[32];
#pragma unroll
  for (int quad = 0; quad < 4; ++quad) {
    const int i = kb * 4 + quad;
    const float ci = cw[quad];
    const float4* wp = (const float4*)(W + (((size_t)i * OD + o) * PD + p) * QD);
    const float4 w0 = wp[0], w1 = wp[1];
    ov[quad * 8 + 0] = f2bf(ci * w0.x); ov[quad * 8 + 1] = f2bf(ci * w0.y);
    ov[quad * 8 + 2] = f2bf(ci * w0.z); ov[quad * 8 + 3] = f2bf(ci * w0.w);
    ov[quad * 8 + 4] = f2bf(ci * w1.x); ov[quad * 8 + 5] = f2bf(ci * w1.y);
    ov[quad * 8 + 6] = f2bf(ci * w1.z); ov[quad * 8 + 7] = f2bf(ci * w1.w);
  }
  int4* dst = (int4*)(Bs + (size_t)t * 32);
  const int4* src = (const int4*)ov;
#pragma unroll
  for (int j = 0; j < 4; ++j) dst[j] = src[j];
}

// ---- phase: prep (bijT init + xB/xT transpose + uniform Bs) ----------------
__device__ void phase_prep(int bid, int nb, int tid, const float* __restrict__ x,
                           const float* __restrict__ W, float* __restrict__ bijT,
                           short* __restrict__ Bs, short* __restrict__ xB,
                           short* __restrict__ xT) {
  __shared__ short tlds[64 * 72];  // [iq_loc][b_loc], pad 72
  for (int t = bid * 256 + tid; t < IO; t += nb * 256) bijT[t] = 0.f;
  for (int vb = bid; vb < TPX; vb += nb) {
    const int bt = vb / (KD / 64), qt = vb % (KD / 64);
    const int b0 = bt * 64, c0 = qt * 64;
    const int row0 = tid >> 4, col4 = (tid & 15) * 4;
#pragma unroll
    for (int j = 0; j < 4; ++j) {
      const int row = row0 + j * 16;
      const float4 v = *(const float4*)(x + (size_t)(b0 + row) * KD + c0 + col4);
      bf16x4 ov;
      ov[0] = f2bf(v.x); ov[1] = f2bf(v.y); ov[2] = f2bf(v.z); ov[3] = f2bf(v.w);
      *(bf16x4*)(xB + (size_t)(b0 + row) * KD + c0 + col4) = ov;
      tlds[(col4 + 0) * 72 + row] = ov[0];
      tlds[(col4 + 1) * 72 + row] = ov[1];
      tlds[(col4 + 2) * 72 + row] = ov[2];
      tlds[(col4 + 3) * 72 + row] = ov[3];
    }
    __syncthreads();
    const int iq = tid & 63, seg = tid >> 6;  // 16 b per (iq,seg)
    const short* src = tlds + iq * 72 + seg * 16;
    short* dst = xT + (size_t)(c0 + iq) * B + b0 + seg * 16;
    *(bf16x8*)dst = *(const bf16x8*)src;
    *(bf16x8*)(dst + 8) = *(const bf16x8*)(src + 8);
    __syncthreads();
  }
  const float cw[4] = {1.0f / (float)IC, 1.0f / (float)IC, 1.0f / (float)IC, 1.0f / (float)IC};
  for (int vb = bid; vb < 180; vb += nb) bs_elem(W, Bs, vb * 256 + tid, cw);
}

// ---- phase: bs rebuild (softmax denom per block + Bs = softmax(bij)*W) -----
__device__ void phase_bs(int bid, int nb, int tid, const float* __restrict__ W,
                         const float* __restrict__ bijT, short* __restrict__ Bs) {
  if (bid >= 180) return;
  __shared__ float wred[4][OD];
  __shared__ float invs[OD];
  const int wave = tid >> 6, lane = tid & 63;
  float lsum[OD];
#pragma unroll
  for (int o = 0; o < OD; ++o) lsum[o] = 0.f;
  for (int i = tid; i < IC; i += 256) {
#pragma unroll
    for (int o = 0; o < OD; ++o) lsum[o] += __expf(bijT[(size_t)o * IC + i]);
  }
#pragma unroll
  for (int o = 0; o < OD; ++o) {
    float s = lsum[o];
#pragma unroll
    for (int st = 1; st < 64; st <<= 1) s += __shfl_xor(s, st);
    if (lane == 0) wred[wave][o] = s;
  }
  __syncthreads();
  if (tid < OD)
    invs[tid] = 1.f / (wred[0][tid] + wred[1][tid] + wred[2][tid] + wred[3][tid]);
  __syncthreads();
  for (int vb = bid; vb < 180; vb += nb) {
    const int t = vb * 256 + tid;
    const int kb = t / 160, n = t % 160;
    const int o = n >> 4;
    const float inv = invs[o];
    const float4 bv = *(const float4*)(bijT + (size_t)o * IC + kb * 4);
    const float cw[4] = {__expf(bv.x) * inv, __expf(bv.y) * inv,
                         __expf(bv.z) * inv, __expf(bv.w) * inv};
    bs_elem(W, Bs, t, cw);
  }
}

// ---- phase: sgemm (s_part[cz][b][n]) ---------------------------------------
__device__ void phase_sgemm(int bid, int nb, int tid, const short* __restrict__ xB,
                            const short* __restrict__ Bs, float* __restrict__ s_part) {
  const int wave = tid >> 6, lane = tid & 63;
  const int ln = lane & 15, quad = lane >> 4;
  for (int vb = bid; vb < 8 * NCS; vb += nb) {
    const int cz = vb % NCS, mb = vb / NCS;
    const int m0 = mb * 64 + wave * 16;
    f32x4 acc[10] = {};
    const short* arow = xB + (size_t)(m0 + ln) * KD + quad * 8;
#pragma unroll
    for (int step = 0; step < KSTEPS; ++step) {
      const int kb = cz * KSTEPS + step;
      const bf16x8 af = *(const bf16x8*)(arow + kb * 32);
      const short* bp = Bs + (size_t)kb * 5120 + ln * 32 + quad * 8;
#pragma unroll
      for (int nt = 0; nt < 10; ++nt) {
        const bf16x8 bf = *(const bf16x8*)(bp + nt * 512);
        acc[nt] = __builtin_amdgcn_mfma_f32_16x16x32_bf16(af, bf, acc[nt], 0, 0, 0);
      }
    }
    float* sp = s_part + (size_t)cz * SOP;
#pragma unroll
    for (int nt = 0; nt < 10; ++nt)
#pragma unroll
      for (int r = 0; r < 4; ++r)
        sp[(size_t)(m0 + quad * 4 + r) * 160 + nt * 16 + ln] = acc[nt][r];
  }
}

// ---- phase: squash (reduce + squash; emit vB or out) -----------------------
__device__ void phase_squash(int bid, int nb, int tid, const float* __restrict__ s_part,
                             short* __restrict__ vB, float* __restrict__ out,
                             int write_out) {
  for (int vb = bid; vb < SOP / 256; vb += nb) {
    const int t = vb * 256 + tid;  // t = b*160 + n
    float sv = 0.f;
#pragma unroll 8
    for (int ch = 0; ch < NCS; ++ch) sv += s_part[(size_t)ch * SOP + t];
    float sq = sv * sv;
#pragma unroll
    for (int m = 1; m < 16; m <<= 1) sq += __shfl_xor(sq, m, 16);
    const float norm = sqrtf(sq + 1e-8f);
    const float val = sv * (sq / ((1.f + sq) * norm));
    if (write_out) {
      out[t] = val;
    } else {
      const int b = t / 160, n = t - b * 160;
      vB[((size_t)(b >> 5) * 160 + n) * 32 + (b & 31)] = f2bf(val);
    }
  }
}

// ---- phase: aggemm (bijT += agreement, A direct from xT) -------------------
__device__ void phase_aggemm(int bid, int nb, int tid, const short* __restrict__ xT,
                             const float* __restrict__ W, const short* __restrict__ vB,
                             float* __restrict__ bijT) {
  const int mt = tid >> 6, lane = tid & 63;
  const int ln = lane & 15, quad = lane >> 4;
  for (int vb = bid; vb < 144 * NCB; vb += nb) {
    const int ig8 = vb % 144, kq = vb / 144;
    f32x4 acc[10] = {};
    const short* arow = xT + (size_t)(ig8 * 64 + mt * 16 + ln) * B + kq * 128 + quad * 8;
#pragma unroll
    for (int kb = 0; kb < 4; ++kb) {
      const bf16x8 af = *(const bf16x8*)(arow + kb * 32);
      const short* bp = vB + ((size_t)(kq * 4 + kb) * 160 + ln) * 32 + quad * 8;
#pragma unroll
      for (int nt = 0; nt < 10; ++nt) {
        const bf16x8 bf = *(const bf16x8*)(bp + nt * 512);
        acc[nt] = __builtin_amdgcn_mfma_f32_16x16x32_bf16(af, bf, acc[nt], 0, 0, 0);
      }
    }
    const int i = ig8 * 8 + mt * 2 + (quad >> 1);
    const int qb = (quad & 1) * 4;
#pragma unroll
    for (int nt = 0; nt < 10; ++nt) {
      const float4 wv = *(const float4*)(W + (((size_t)i * OD + nt) * PD + ln) * QD + qb);
      float pa = acc[nt][0] * wv.x + acc[nt][1] * wv.y + acc[nt][2] * wv.z + acc[nt][3] * wv.w;
      pa += __shfl_xor(pa, 1); pa += __shfl_xor(pa, 2); pa += __shfl_xor(pa, 4);
      pa += __shfl_xor(pa, 8); pa += __shfl_xor(pa, 16);
      if ((lane & 31) == 0)
        atomicAdd(&bijT[(size_t)nt * IC + i], pa * (1.0f / (float)B));
    }
  }
}

// ---- mega: all phases, grid.sync between -----------------------------------
__global__ __launch_bounds__(256, 2) void mega_kernel(const float* __restrict__ x,
                                                      const float* __restrict__ W,
                                                      float* __restrict__ out,
                                                      float* __restrict__ s_part,
                                                      float* __restrict__ bijT,
                                                      short* __restrict__ vB,
                                                      short* __restrict__ Bs,
                                                      short* __restrict__ xB,
                                                      short* __restrict__ xT) {
  cg::grid_group grid = cg::this_grid();
  const int bid = blockIdx.x, nb = gridDim.x, tid = threadIdx.x;
  phase_prep(bid, nb, tid, x, W, bijT, Bs, xB, xT);
  grid.sync();
  for (int iter = 0; iter < 3; ++iter) {
    if (iter) {
      phase_bs(bid, nb, tid, W, bijT, Bs);
      grid.sync();
    }
    phase_sgemm(bid, nb, tid, xB, Bs, s_part);
    grid.sync();
    phase_squash(bid, nb, tid, s_part, vB, out, iter == 2);
    if (iter == 2) break;
    grid.sync();
    phase_aggemm(bid, nb, tid, xT, W, vB, bijT);
    grid.sync();
  }
}

// ---- fallback wrappers (11-dispatch path) ----------------------------------
__global__ __launch_bounds__(256) void prep_kernel(const float* __restrict__ x,
                                                   const float* __restrict__ W,
                                                   float* __restrict__ bijT,
                                                   short* __restrict__ Bs,
                                                   short* __restrict__ xB,
                                                   short* __restrict__ xT) {
  phase_prep(blockIdx.x, gridDim.x, threadIdx.x, x, W, bijT, Bs, xB, xT);
}
__global__ __launch_bounds__(256) void rbn_kernel(const float* __restrict__ W,
                                                  const float* __restrict__ bijT,
                                                  short* __restrict__ Bs) {
  phase_bs(blockIdx.x, gridDim.x, threadIdx.x, W, bijT, Bs);
}
__global__ __launch_bounds__(256) void sgemm_kernel(const short* __restrict__ xB,
                                                    const short* __restrict__ Bs,
                                                    float* __restrict__ s_part) {
  phase_sgemm(blockIdx.x, gridDim.x, threadIdx.x, xB, Bs, s_part);
}
__global__ __launch_bounds__(256) void squash_kernel(const float* __restrict__ s_part,
                                                     short* __restrict__ vB,
                                                     float* __restrict__ out,
                                                     int write_out) {
  phase_squash(blockIdx.x, gridDim.x, threadIdx.x, s_part, vB, out, write_out);
}
__global__ __launch_bounds__(256) void aggemm_kernel(const short* __restrict__ xT,
                                                     const float* __restrict__ W,
                                                     const short* __restrict__ vB,
                                                     float* __restrict__ bijT) {
  phase_aggemm(blockIdx.x, gridDim.x, threadIdx.x, xT, W, vB, bijT);
}

// ---- launch ----------------------------------------------------------------
extern "C" void kernel_launch(void* const* d_in, const int* in_sizes, int n_in,
                              void* d_out, int out_size, void* d_ws, size_t ws_size,
                              hipStream_t stream) {
  const float* x = (const float*)d_in[0];  // [512,1152,8] fp32
  const float* W = (const float*)d_in[1];  // [1152,10,16,8] fp32
  float* out = (float*)d_out;              // [512,10,16] fp32

  float* ws = (float*)d_ws;
  float* s_part = ws;                                  // 72*81920 f
  float* bijT = s_part + (size_t)NCS * SOP;            // 11520 f
  short* vB = (short*)(bijT + IO);                     // 16*160*32 shorts
  short* Bs = vB + (size_t)16 * 160 * 32;              // 288*160*32 shorts
  short* xB = Bs + (size_t)NKB * 160 * 32;             // 512*9216 shorts
  short* xT = xB + (size_t)B * KD;                     // 9216*512 shorts

  // decide cooperative grid once (host-side queries only; capture-safe)
  static int g_nb = 0;
  if (g_nb == 0) {
    int dev = 0, ncu = 0, occ = 0;
    hipGetDevice(&dev);
    hipDeviceGetAttribute(&ncu, hipDeviceAttributeMultiprocessorCount, dev);
    hipOccupancyMaxActiveBlocksPerMultiprocessor(&occ, (const void*)mega_kernel, 256, 0);
    int cap = occ * ncu;
    g_nb = cap < NBTARGET ? cap : NBTARGET;
    if (g_nb < 8) g_nb = -1;  // absurd -> fallback path
  }

  bool coop_ok = false;
  if (g_nb > 0) {
    void* args[] = {(void*)&x, (void*)&W, (void*)&out, (void*)&s_part, (void*)&bijT,
                    (void*)&vB, (void*)&Bs, (void*)&xB, (void*)&xT};
    hipError_t e = hipLaunchCooperativeKernel((const void*)mega_kernel, dim3(g_nb),
                                              dim3(256), args, 0, stream);
    if (e == hipSuccess) coop_ok = true;
    else g_nb = -1;  // never retry
  }
  if (!coop_ok) {
    prep_kernel<<<TPX, 256, 0, stream>>>(x, W, bijT, Bs, xB, xT);
    sgemm_kernel<<<8 * NCS, 256, 0, stream>>>(xB, Bs, s_part);
    squash_kernel<<<SOP / 256, 256, 0, stream>>>(s_part, vB, out, 0);
    aggemm_kernel<<<144 * NCB, 256, 0, stream>>>(xT, W, vB, bijT);
    rbn_kernel<<<180, 256, 0, stream>>>(W, bijT, Bs);
    sgemm_kernel<<<8 * NCS, 256, 0, stream>>>(xB, Bs, s_part);
    squash_kernel<<<SOP / 256, 256, 0, stream>>>(s_part, vB, out, 0);
    aggemm_kernel<<<144 * NCB, 256, 0, stream>>>(xT, W, vB, bijT);
    rbn_kernel<<<180, 256, 0, stream>>>(W, bijT, Bs);
    sgemm_kernel<<<8 * NCS, 256, 0, stream>>>(xB, Bs, s_part);
    squash_kernel<<<SOP / 256, 256, 0, stream>>>(s_part, vB, out, 1);
  }
}

// Round 5
// 208.568 us; speedup vs baseline: 3.8115x; 3.8115x over previous
//
#include <hip/hip_runtime.h>
#include <hip/hip_bf16.h>

// DigitCaps dynamic routing. Output fp32.
// R18: 6 dispatches (was 11). R17 post-mortem: grid.sync ~80us each on gfx950
// (XCD L2 wb+inv per block) -> cooperative fusion dead. Instead:
//  - deferred softmax norm: Bs = exp(bij)*W; s /= esum[o] in fp32 pre-squash.
//  - fuse1 = sgemm(full K per block, 4 waves x 72 steps) + LDS reduce + squash.
//    s_part buffer + squash dispatch deleted.
//  - agg2 = agreement MFMA + atomicAdd bijT (returned, asm-sink ordered) +
//    per-ig8 last-block finisher rebuilds its 2 Bs k-blocks (agent-scope
//    atomic loads of 80 bij values; no fences, no wbl2/inv).
// Chain: prep | fuse1 | agg2 | fuse1 | agg2 | fuse1.
#define B 512
#define IC 1152
#define QD 8
#define OD 10
#define PD 16
#define KD (IC * QD)       // 9216
#define NKB (KD / 32)      // 288 K32 blocks
#define NCB 4              // b-chunks for agreement GEMM (128 each)
#define IO (IC * OD)       // 11520
#define TPX ((B / 64) * (KD / 64))  // 8*144 = 1152 transpose tiles

typedef short bf16x8 __attribute__((ext_vector_type(8)));
typedef short bf16x4 __attribute__((ext_vector_type(4)));
typedef float f32x4 __attribute__((ext_vector_type(4)));

__device__ __forceinline__ short f2bf(float f) {
  union { float f; unsigned u; } x;
  x.f = f;
  unsigned r = x.u + 0x7FFFu + ((x.u >> 16) & 1u);  // RNE to bf16
  return (short)(r >> 16);
}

// ---------------- prep: xB + xT transpose, Bs = bf16(W), zero bijT/ctr ------
__global__ __launch_bounds__(256) void prep_kernel(const float* __restrict__ x,
                                                   const float* __restrict__ W,
                                                   float* __restrict__ bijT,
                                                   int* __restrict__ ctr,
                                                   short* __restrict__ Bs,
                                                   short* __restrict__ xB,
                                                   short* __restrict__ xT) {
  const int bid = blockIdx.x, tid = threadIdx.x;
  if (bid < TPX) {
    // 64 b x 64 iq tile: read x fp32, emit xB (linear bf16) + xT (transposed)
    __shared__ short lds[64 * 72];  // [iq_loc][b_loc], pad 72
    const int bt = bid / (KD / 64), qt = bid % (KD / 64);
    const int b0 = bt * 64, c0 = qt * 64;
    const int row0 = tid >> 4, col4 = (tid & 15) * 4;
#pragma unroll
    for (int j = 0; j < 4; ++j) {
      const int row = row0 + j * 16;
      const float4 v = *(const float4*)(x + (size_t)(b0 + row) * KD + c0 + col4);
      bf16x4 ov;
      ov[0] = f2bf(v.x); ov[1] = f2bf(v.y); ov[2] = f2bf(v.z); ov[3] = f2bf(v.w);
      *(bf16x4*)(xB + (size_t)(b0 + row) * KD + c0 + col4) = ov;
      lds[(col4 + 0) * 72 + row] = ov[0];
      lds[(col4 + 1) * 72 + row] = ov[1];
      lds[(col4 + 2) * 72 + row] = ov[2];
      lds[(col4 + 3) * 72 + row] = ov[3];
    }
    __syncthreads();
    const int iq = tid & 63, seg = tid >> 6;  // 16 b per (iq,seg)
    const short* src = lds + iq * 72 + seg * 16;
    short* dst = xT + (size_t)(c0 + iq) * B + b0 + seg * 16;
    *(bf16x8*)dst = *(const bf16x8*)src;
    *(bf16x8*)(dst + 8) = *(const bf16x8*)(src + 8);
    return;
  }
  const int t = (bid - TPX) * 256 + tid;  // 0..46079
  if (t < IO) bijT[t] = 0.f;              // cumulative bij zero-init
  if (t < 144) ctr[t] = 0;                // per-ig8 completion counters
  const int kb = t / 160, n = t % 160;
  const int o = n >> 4, p = n & 15;
  short ov[32];
#pragma unroll
  for (int quad = 0; quad < 4; ++quad) {
    const int i = kb * 4 + quad;
    const float4* wp = (const float4*)(W + (((size_t)i * OD + o) * PD + p) * QD);
    const float4 w0 = wp[0], w1 = wp[1];
    ov[quad * 8 + 0] = f2bf(w0.x); ov[quad * 8 + 1] = f2bf(w0.y);
    ov[quad * 8 + 2] = f2bf(w0.z); ov[quad * 8 + 3] = f2bf(w0.w);
    ov[quad * 8 + 4] = f2bf(w1.x); ov[quad * 8 + 5] = f2bf(w1.y);
    ov[quad * 8 + 6] = f2bf(w1.z); ov[quad * 8 + 7] = f2bf(w1.w);
  }
  int4* dst = (int4*)(Bs + (size_t)t * 32);
  const int4* src = (const int4*)ov;
#pragma unroll
  for (int j = 0; j < 4; ++j) dst[j] = src[j];
}

// ---------------- fuse1: s (full K) + /esum + squash -> vB or out -----------
// grid (16 mb, 5 og). Block: 32 b-rows x 2 o (32 n). 4 waves split K 4x72.
__global__ __launch_bounds__(256) void fuse1_kernel(const short* __restrict__ xB,
                                                    const short* __restrict__ Bs,
                                                    const float* __restrict__ bijT,
                                                    short* __restrict__ vB,
                                                    float* __restrict__ out,
                                                    int write_out) {
  __shared__ float sbuf[4][32][33];  // +1 pad
  __shared__ float wr[4][2];
  const int tid = threadIdx.x, wave = tid >> 6, lane = tid & 63;
  const int ln = lane & 15, quad = lane >> 4;
  const int mb = blockIdx.x, o0 = blockIdx.y * 2;
  // softmax denominators for this block's 2 o's (no max-sub: |bij| ~ O(1))
  float ls0 = 0.f, ls1 = 0.f;
  for (int i = tid; i < IC; i += 256) {
    ls0 += __expf(bijT[(size_t)o0 * IC + i]);
    ls1 += __expf(bijT[(size_t)(o0 + 1) * IC + i]);
  }
#pragma unroll
  for (int st = 1; st < 64; st <<= 1) {
    ls0 += __shfl_xor(ls0, st);
    ls1 += __shfl_xor(ls1, st);
  }
  if (lane == 0) { wr[wave][0] = ls0; wr[wave][1] = ls1; }
  // main GEMM: wave handles kb in [wave*72, wave*72+72)
  const int m0 = mb * 32;
  f32x4 acc00 = {}, acc01 = {}, acc10 = {}, acc11 = {};
  const short* arow0 = xB + (size_t)(m0 + ln) * KD + quad * 8;
  const short* arow1 = arow0 + (size_t)16 * KD;
  const short* bbase = Bs + (size_t)wave * 72 * 5120 + o0 * 512 + ln * 32 + quad * 8;
#pragma unroll 8
  for (int step = 0; step < 72; ++step) {
    const int kb = wave * 72 + step;
    const bf16x8 a0 = *(const bf16x8*)(arow0 + (size_t)kb * 32);
    const bf16x8 a1 = *(const bf16x8*)(arow1 + (size_t)kb * 32);
    const short* bp = bbase + (size_t)step * 5120;
    const bf16x8 b0 = *(const bf16x8*)bp;
    const bf16x8 b1 = *(const bf16x8*)(bp + 512);
    acc00 = __builtin_amdgcn_mfma_f32_16x16x32_bf16(a0, b0, acc00, 0, 0, 0);
    acc10 = __builtin_amdgcn_mfma_f32_16x16x32_bf16(a1, b0, acc10, 0, 0, 0);
    acc01 = __builtin_amdgcn_mfma_f32_16x16x32_bf16(a0, b1, acc01, 0, 0, 0);
    acc11 = __builtin_amdgcn_mfma_f32_16x16x32_bf16(a1, b1, acc11, 0, 0, 0);
  }
  // stash per-wave partials (C layout: row = quad*4+r, col = nt*16+ln)
#pragma unroll
  for (int r = 0; r < 4; ++r) {
    sbuf[wave][quad * 4 + r][ln] = acc00[r];
    sbuf[wave][quad * 4 + r][16 + ln] = acc01[r];
    sbuf[wave][16 + quad * 4 + r][ln] = acc10[r];
    sbuf[wave][16 + quad * 4 + r][16 + ln] = acc11[r];
  }
  __syncthreads();
  const float inv0 = 1.f / (wr[0][0] + wr[1][0] + wr[2][0] + wr[3][0]);
  const float inv1 = 1.f / (wr[0][1] + wr[1][1] + wr[2][1] + wr[3][1]);
  const int p = tid & 15, r0 = tid >> 4;
#pragma unroll
  for (int rr = 0; rr < 2; ++rr) {
    const int row = r0 + rr * 16;
#pragma unroll
    for (int ol = 0; ol < 2; ++ol) {
      const int col = ol * 16 + p;
      float sv = (sbuf[0][row][col] + sbuf[1][row][col] + sbuf[2][row][col] +
                  sbuf[3][row][col]) * (ol ? inv1 : inv0);
      float sq = sv * sv;
#pragma unroll
      for (int m = 1; m < 16; m <<= 1) sq += __shfl_xor(sq, m, 16);
      const float norm = sqrtf(sq + 1e-8f);
      const float val = sv * (sq / ((1.f + sq) * norm));
      const int b = m0 + row, n = (o0 + ol) * 16 + p;
      if (write_out) {
        out[(size_t)b * 160 + n] = val;
      } else {
        vB[((size_t)(b >> 5) * 160 + n) * 32 + (b & 31)] = f2bf(val);
      }
    }
  }
}

// ---------------- agg2: bijT += agreement; last kq-block rebuilds Bs slice --
// grid (144 ig8, 4 kq). G[m=(i8q),(n=o*16+p)] = sum_b xT[iq][b]*v[b][op].
__global__ __launch_bounds__(256) void agg2_kernel(const short* __restrict__ xT,
                                                   const float* __restrict__ W,
                                                   const short* __restrict__ vB,
                                                   float* __restrict__ bijT,
                                                   short* __restrict__ Bs,
                                                   int* __restrict__ ctr) {
  const int tid = threadIdx.x;
  const int ig8 = blockIdx.x, kq = blockIdx.y;
  const int mt = tid >> 6, lane = tid & 63;
  const int ln = lane & 15, quad = lane >> 4;
  f32x4 acc[10] = {};
  const short* arow = xT + (size_t)(ig8 * 64 + mt * 16 + ln) * B + kq * 128 + quad * 8;
#pragma unroll
  for (int kb = 0; kb < 4; ++kb) {
    const bf16x8 af = *(const bf16x8*)(arow + kb * 32);
    const short* bp = vB + ((size_t)(kq * 4 + kb) * 160 + ln) * 32 + quad * 8;
#pragma unroll
    for (int nt = 0; nt < 10; ++nt) {
      const bf16x8 bf = *(const bf16x8*)(bp + nt * 512);
      acc[nt] = __builtin_amdgcn_mfma_f32_16x16x32_bf16(af, bf, acc[nt], 0, 0, 0);
    }
  }
  // epilogue: contract G with W -> agreement; RETURNED atomics (ordering!)
  const int i = ig8 * 8 + mt * 2 + (quad >> 1);
  const int qb = (quad & 1) * 4;
  float rsum = 0.f;
#pragma unroll
  for (int nt = 0; nt < 10; ++nt) {
    const float4 wv = *(const float4*)(W + (((size_t)i * OD + nt) * PD + ln) * QD + qb);
    float pa = acc[nt][0] * wv.x + acc[nt][1] * wv.y + acc[nt][2] * wv.z + acc[nt][3] * wv.w;
    pa += __shfl_xor(pa, 1); pa += __shfl_xor(pa, 2); pa += __shfl_xor(pa, 4);
    pa += __shfl_xor(pa, 8); pa += __shfl_xor(pa, 16);
    if ((lane & 31) == 0)
      rsum += atomicAdd(&bijT[(size_t)nt * IC + i], pa * (1.0f / (float)B));
  }
  // consume returns: forces vmcnt-wait -> adds complete at coherence point
  asm volatile("" :: "v"(rsum));
  __syncthreads();
  __shared__ int flag;
  __shared__ float eL[8][OD];
  if (tid == 0)
    flag = (__hip_atomic_fetch_add(&ctr[ig8], 1, __ATOMIC_RELAXED,
                                   __HIP_MEMORY_SCOPE_AGENT) == NCB - 1) ? 1 : 0;
  __syncthreads();
  if (!flag) return;
  // finisher: rebuild Bs k-blocks [ig8*2, ig8*2+1] = exp(bij)*W (unnormalized)
  if (tid < 8 * OD) {
    const int il = tid / OD, o = tid - il * OD;
    const float bv = __hip_atomic_load(&bijT[(size_t)o * IC + ig8 * 8 + il],
                                       __ATOMIC_RELAXED, __HIP_MEMORY_SCOPE_AGENT);
    eL[il][o] = __expf(bv);
  }
  if (tid == 0)
    __hip_atomic_store(&ctr[ig8], 0, __ATOMIC_RELAXED, __HIP_MEMORY_SCOPE_AGENT);
  __syncthreads();
  for (int vb = tid; vb < 320; vb += 256) {
    const int kbl = vb / 160, n = vb - kbl * 160;
    const int kb = ig8 * 2 + kbl;
    const int o = n >> 4, pp = n & 15;
    short ov[32];
#pragma unroll
    for (int q4 = 0; q4 < 4; ++q4) {
      const int ii = kb * 4 + q4;
      const float ci = eL[ii - ig8 * 8][o];
      const float4* wp = (const float4*)(W + (((size_t)ii * OD + o) * PD + pp) * QD);
      const float4 w0 = wp[0], w1 = wp[1];
      ov[q4 * 8 + 0] = f2bf(ci * w0.x); ov[q4 * 8 + 1] = f2bf(ci * w0.y);
      ov[q4 * 8 + 2] = f2bf(ci * w0.z); ov[q4 * 8 + 3] = f2bf(ci * w0.w);
      ov[q4 * 8 + 4] = f2bf(ci * w1.x); ov[q4 * 8 + 5] = f2bf(ci * w1.y);
      ov[q4 * 8 + 6] = f2bf(ci * w1.z); ov[q4 * 8 + 7] = f2bf(ci * w1.w);
    }
    int4* dst = (int4*)(Bs + (size_t)(kb * 160 + n) * 32);
    const int4* src = (const int4*)ov;
#pragma unroll
    for (int j = 0; j < 4; ++j) dst[j] = src[j];
  }
}

// ---------------- launch: 6 dispatches --------------------------------------

extern "C" void kernel_launch(void* const* d_in, const int* in_sizes, int n_in,
                              void* d_out, int out_size, void* d_ws, size_t ws_size,
                              hipStream_t stream) {
  const float* x = (const float*)d_in[0];  // [512,1152,8] fp32
  const float* W = (const float*)d_in[1];  // [1152,10,16,8] fp32
  float* out = (float*)d_out;              // [512,10,16] fp32

  // workspace ~22 MB; every buffer written before read per call
  float* bijT = (float*)d_ws;                          // 11520 f
  int* ctr = (int*)(bijT + IO);                        // 144 i (pad 160)
  short* vB = (short*)(ctr + 160);                     // 16*160*32 shorts
  short* Bs = vB + (size_t)16 * 160 * 32;              // 288*160*32 shorts
  short* xB = Bs + (size_t)NKB * 160 * 32;             // 512*9216 shorts
  short* xT = xB + (size_t)B * KD;                     // 9216*512 shorts

  const dim3 fgrid(16, 5);
  const dim3 agrid(144, NCB);

  prep_kernel<<<TPX + 180, 256, 0, stream>>>(x, W, bijT, ctr, Bs, xB, xT);
  fuse1_kernel<<<fgrid, 256, 0, stream>>>(xB, Bs, bijT, vB, out, 0);   // iter 1
  agg2_kernel<<<agrid, 256, 0, stream>>>(xT, W, vB, bijT, Bs, ctr);
  fuse1_kernel<<<fgrid, 256, 0, stream>>>(xB, Bs, bijT, vB, out, 0);   // iter 2
  agg2_kernel<<<agrid, 256, 0, stream>>>(xT, W, vB, bijT, Bs, ctr);
  fuse1_kernel<<<fgrid, 256, 0, stream>>>(xB, Bs, bijT, vB, out, 1);   // iter 3
}